// Round 7
// baseline (11860.690 us; speedup 1.0000x reference)
//
#include <hip/hip_runtime.h>
#include <stdint.h>

typedef unsigned short u16;
typedef __attribute__((ext_vector_type(8))) __bf16 bf16x8;
typedef __attribute__((ext_vector_type(4))) float f32x4;

#define NBLK 64          // recurrence blocks (each owns 16 h-columns)
#define TSTEPS 1000

__device__ __forceinline__ u16 f2bf(float f) {
    uint32_t u = __builtin_bit_cast(uint32_t, f);
    u += 0x7fffu + ((u >> 16) & 1u);
    return (u16)(u >> 16);
}
__device__ __forceinline__ float bf2f(u16 s) {
    uint32_t u = ((uint32_t)s) << 16;
    return __builtin_bit_cast(float, u);
}

// quaternion block tables: W[ci*256+a][cj*256+b] = sgn[ci][cj] * w[comp[ci][cj]][a][b]
__device__ const int   q_comp[4][4] = {{0,1,2,3},{1,0,3,2},{2,3,0,1},{3,2,1,0}};
__device__ const float q_sgn [4][4] = {{ 1.f, 1.f, 1.f, 1.f},
                                       {-1.f, 1.f, 1.f,-1.f},
                                       {-1.f,-1.f, 1.f, 1.f},
                                       {-1.f, 1.f,-1.f, 1.f}};

// ---------------- x (f32) -> bf16 ----------------
__global__ void k_convert_x(const float* __restrict__ x, u16* __restrict__ xb, int n8) {
    int i = blockIdx.x * blockDim.x + threadIdx.x;
    if (i >= n8) return;
    const float4* p = (const float4*)x;
    float4 v0 = p[2*i], v1 = p[2*i + 1];
    u16 o[8];
    o[0]=f2bf(v0.x); o[1]=f2bf(v0.y); o[2]=f2bf(v0.z); o[3]=f2bf(v0.w);
    o[4]=f2bf(v1.x); o[5]=f2bf(v1.y); o[6]=f2bf(v1.z); o[7]=f2bf(v1.w);
    *(uint4*)(xb + (size_t)i*8) = *(uint4*)o;
}

// ---------------- build WqT [2048][1024] bf16 (row n = output col, k-contiguous) -----
__global__ void k_build_wq(const float* __restrict__ wh_w, const float* __restrict__ wz_w,
                           u16* __restrict__ wqT) {
    int tid = blockIdx.x * blockDim.x + threadIdx.x;   // 0..262143
    int n = tid >> 7, kg = tid & 127;
    const float* src = (n < 1024) ? wh_w : wz_w;
    int nn = n & 1023;
    int cj = nn >> 8, b = nn & 255;
    int k0 = kg << 3;
    int ci = k0 >> 8, a0 = k0 & 255;
    int c = q_comp[ci][cj];
    float s = q_sgn[ci][cj];
    const float* sp = src + c*65536 + a0*256 + b;
    u16 o[8];
    #pragma unroll
    for (int e = 0; e < 8; ++e) o[e] = f2bf(s * sp[e*256]);
    *(uint4*)(wqT + (size_t)n*1024 + k0) = *(uint4*)o;
}

// ---------------- build U pack: [blk][nt][ks][lane][8] bf16 (MFMA B-fragment order) --
__global__ void k_build_upack(const float* __restrict__ uh_w, const float* __restrict__ uz_w,
                              u16* __restrict__ upack) {
    int tid = blockIdx.x * blockDim.x + threadIdx.x;   // 0..262143
    int l   = tid & 63;
    int ks  = (tid >> 6) & 31;
    int nt  = (tid >> 11) & 1;
    int blk = tid >> 12;
    int j   = (blk << 4) + (l & 15);        // U column
    int k0  = (ks << 5) + ((l >> 4) << 3);  // U row base
    int ci = k0 >> 8, a0 = k0 & 255;
    int cj = j >> 8, b = j & 255;
    const float* src = nt ? uz_w : uh_w;
    int c = q_comp[ci][cj];
    float s = q_sgn[ci][cj];
    const float* sp = src + c*65536 + a0*256 + b;
    u16 o[8];
    #pragma unroll
    for (int e = 0; e < 8; ++e) o[e] = f2bf(s * sp[e*256]);
    *(uint4*)(upack + (size_t)tid*8) = *(uint4*)o;
}

// ---------------- phase-1 GEMM: C[32000][2048] bf16 = x_bf16 @ WqT^T + bias ----------
__global__ __launch_bounds__(256) void k_gemm(
        const u16* __restrict__ A, const u16* __restrict__ Bt,
        const float* __restrict__ whb, const float* __restrict__ wzb,
        u16* __restrict__ C)
{
    __shared__ __align__(16) u16 lsA[128*32];
    __shared__ __align__(16) u16 lsB[128*32];
    int bid = blockIdx.x;
    int swz = (bid & 7) * 500 + (bid >> 3);   // XCD swizzle (4000 = 8*500, bijective)
    int mi = swz >> 4, ni = swz & 15;
    int m0 = mi << 7, n0 = ni << 7;
    int tid = threadIdx.x;
    int w = tid >> 6, l = tid & 63;
    int wm = w >> 1, wn = w & 1;
    f32x4 acc[4][4];
    #pragma unroll
    for (int i = 0; i < 4; ++i)
        #pragma unroll
        for (int j = 0; j < 4; ++j) acc[i][j] = (f32x4){0.f,0.f,0.f,0.f};

    for (int kt = 0; kt < 32; ++kt) {
        int k0 = kt << 5;
        #pragma unroll
        for (int r = 0; r < 2; ++r) {
            int c = r*256 + w*64 + l;
            const u16* ga = A + (size_t)(m0 + (c >> 2))*1024 + k0 + (c & 3)*8;
            __builtin_amdgcn_global_load_lds(
                (const __attribute__((address_space(1))) uint32_t*)ga,
                (__attribute__((address_space(3))) uint32_t*)((char*)lsA + r*4096 + w*1024),
                16, 0, 0);
            const u16* gb = Bt + (size_t)(n0 + (c >> 2))*1024 + k0 + (c & 3)*8;
            __builtin_amdgcn_global_load_lds(
                (const __attribute__((address_space(1))) uint32_t*)gb,
                (__attribute__((address_space(3))) uint32_t*)((char*)lsB + r*4096 + w*1024),
                16, 0, 0);
        }
        __syncthreads();
        uint4 af[4], bfr[4];
        #pragma unroll
        for (int i = 0; i < 4; ++i) {
            int rowa = wm*64 + i*16 + (l & 15);
            af[i]  = *(const uint4*)((const char*)lsA + rowa*64 + (l >> 4)*16);
            int rowb = wn*64 + i*16 + (l & 15);
            bfr[i] = *(const uint4*)((const char*)lsB + rowb*64 + (l >> 4)*16);
        }
        #pragma unroll
        for (int i = 0; i < 4; ++i)
            #pragma unroll
            for (int j = 0; j < 4; ++j)
                acc[i][j] = __builtin_amdgcn_mfma_f32_16x16x32_bf16(
                    __builtin_bit_cast(bf16x8, af[i]),
                    __builtin_bit_cast(bf16x8, bfr[j]),
                    acc[i][j], 0, 0, 0);
        __syncthreads();
    }
    #pragma unroll
    for (int j = 0; j < 4; ++j) {
        int col = n0 + wn*64 + j*16 + (l & 15);
        float bias = (col < 1024) ? whb[col] : wzb[col - 1024];
        #pragma unroll
        for (int i = 0; i < 4; ++i) {
            int rowm = m0 + wm*64 + i*16 + ((l >> 4) << 2);
            #pragma unroll
            for (int q = 0; q < 4; ++q)
                C[(size_t)(rowm + q)*2048 + col] = f2bf(acc[i][j][q] + bias);
        }
    }
}

// ---------------- phase-2: the recurrence -------------------------------------------
// 64 blocks x 128 threads (2 waves). Block owns 16 h-columns; U slice in LDS.
// h exchanged as TAGGED u32 ((t<<16)|bf16) in consumer-packed coalesced layout.
// ALL loop vmem is asm-volatile-pinned so vmcnt FIFO counts are exact:
//   per step: PF(8 ld) | chain: rolling-window ISSUE + counted vmcnt | serial retry
//   epilogue: publish(4 st) ISSUE(16 ld) deferred-out(4 st) CPJ(v_mov handoff)
// Deferred out-write: region t-1 written during step t (transitively gated on
// tag t+1 publishes => all region-t prefetches retired; one full step of slack).
// t=0's dummy deferred write targets the DEAD xb buffer (inside proven ws
// footprint), keeping the FIFO uniform without touching region 999.

#define DECL4(A,B,C,D) uint4 ha##A, hc##A, ha##B, hc##B, ha##C, hc##C, ha##D, hc##D;

#define ISSUE(KS) \
    asm volatile("global_load_dwordx4 %0, %2, off sc0 sc1\n\t" \
                 "global_load_dwordx4 %1, %2, off offset:16 sc0 sc1" \
                 : "=v"(ha##KS), "=v"(hc##KS) : "v"(icur) : "memory"); \
    icur += 512;

#define VAL8(HA, HC) \
    (((HA.x^TT)|(HA.y^TT)|(HA.z^TT)|(HA.w^TT)| \
      (HC.x^TT)|(HC.y^TT)|(HC.z^TT)|(HC.w^TT)) >> 16)

#define DOMFMA(HA, HC, KS) { \
    uint32_t p0 = __builtin_amdgcn_perm(HA.y, HA.x, 0x05040100u); \
    uint32_t p1 = __builtin_amdgcn_perm(HA.w, HA.z, 0x05040100u); \
    uint32_t p2 = __builtin_amdgcn_perm(HC.y, HC.x, 0x05040100u); \
    uint32_t p3 = __builtin_amdgcn_perm(HC.w, HC.z, 0x05040100u); \
    uint4 av4 = make_uint4(p0, p1, p2, p3); \
    bf16x8 av = __builtin_bit_cast(bf16x8, av4); \
    bf16x8 bh = __builtin_bit_cast(bf16x8, ubs[(KS)*64 + l]); \
    bf16x8 bz = __builtin_bit_cast(bf16x8, ubs[(32 + (KS))*64 + l]); \
    if (((KS) & 1) == 0) { \
        acch0 = __builtin_amdgcn_mfma_f32_16x16x32_bf16(av, bh, acch0, 0, 0, 0); \
        accz0 = __builtin_amdgcn_mfma_f32_16x16x32_bf16(av, bz, accz0, 0, 0, 0); \
    } else { \
        acch1 = __builtin_amdgcn_mfma_f32_16x16x32_bf16(av, bh, acch1, 0, 0, 0); \
        accz1 = __builtin_amdgcn_mfma_f32_16x16x32_bf16(av, bz, accz1, 0, 0, 0); \
    } }

#define PROC_I(KS, KSP8, VM) \
    asm volatile("s_waitcnt vmcnt(" #VM ")" ::: "memory"); \
    __builtin_amdgcn_sched_barrier(0); \
    { bool okc = __all(VAL8(ha##KS, hc##KS) == 0); \
      ISSUE(KSP8) \
      if (okc) { DOMFMA(ha##KS, hc##KS, KS) } else stale |= (1u << (KS)); }

#define PROC_N(KS, VM) \
    asm volatile("s_waitcnt vmcnt(" #VM ")" ::: "memory"); \
    __builtin_amdgcn_sched_barrier(0); \
    { bool okc = __all(VAL8(ha##KS, hc##KS) == 0); \
      if (okc) { DOMFMA(ha##KS, hc##KS, KS) } else stale |= (1u << (KS)); }

// pinned prefetch of next step's projections (2 loads per q: wh @0, wz @2048B)
#define PF(Q) \
    asm volatile("global_load_ushort %0, %2, off\n\t" \
                 "global_load_ushort %1, %2, off offset:2048" \
                 : "=v"(nwh[Q]), "=v"(nwz[Q]) : "v"(pa + (Q)*4096) : "memory");

// pinned register hand-off (volatile asm => ordered after the chain's vmcnt(0))
#define CPJ(Q) \
    asm volatile("v_mov_b32 %0, %2\n\tv_mov_b32 %1, %3" \
                 : "=v"(whu[Q]), "=v"(wzu[Q]) : "v"(nwh[Q]), "v"(nwz[Q]));

__global__ __launch_bounds__(128, 1) void k_rec(
        const u16* __restrict__ upack,
        uint32_t* __restrict__ hb32,       // 2 * 32768 tagged u32; both parities zeroed
        const float* __restrict__ drop,    // [32][1024]
        float* __restrict__ out,           // d_out; also holds phase-1 bf16 [32000][2048]
        float* __restrict__ sink)          // t=0 dummy deferred-write target (dead xb)
{
    __shared__ __align__(16) uint4 ubs[4096];     // 64 KB U slice
    const int tid = threadIdx.x;
    const int blk = blockIdx.x;
    const int mt = tid >> 6, l = tid & 63;

    const uint4* ug = (const uint4*)upack + (size_t)blk*4096;
    #pragma unroll 4
    for (int r = 0; r < 32; ++r) ubs[r*128 + tid] = ug[r*128 + tid];

    const int j  = (blk << 4) + (l & 15);            // owned h column
    const int b0 = (mt << 4) + ((l >> 4) << 2);      // producer batch-row base
    float h[4]    = {0.f,0.f,0.f,0.f};
    float pout[4] = {0.f,0.f,0.f,0.f};               // deferred out values (h of t-1)
    float dm[4];
    #pragma unroll
    for (int q = 0; q < 4; ++q) dm[q] = drop[(b0 + q)*1024 + j];

    const u16* pj = (const u16*)out;   // [32000][2048] bf16 (phase-1 result)
    uint32_t whu[4], wzu[4];
    #pragma unroll
    for (int q = 0; q < 4; ++q) {      // projections for t=0 (pre-publish: race-free)
        size_t rowp = (size_t)(b0 + q) * 2048;
        whu[q] = pj[rowp + j];
        wzu[q] = pj[rowp + 1024 + j];
    }
    // consumer base (u32 units) for chunk 0; chunk stride = 512 u32 (2 KB)
    const uint32_t cb = (uint32_t)(mt*2048 + l) * 8u;
    // producer base (u32 units) for q=0; q stride = 8 u32
    const uint32_t pb = (uint32_t)(((mt*32 + (j >> 5))*64
                       + ((l >> 4) << 2) + ((j >> 3) & 3)*16)*8 + (j & 7));

    __syncthreads();   // ubs ready (only sync in the kernel)

    DECL4(0,1,2,3) DECL4(4,5,6,7) DECL4(8,9,10,11) DECL4(12,13,14,15)
    DECL4(16,17,18,19) DECL4(20,21,22,23) DECL4(24,25,26,27) DECL4(28,29,30,31)

    const uint32_t* icur = hb32 + cb;   // parity 0 (zeroed: tag 0, h0 = 0)
    ISSUE(0) ISSUE(1) ISSUE(2) ISSUE(3) ISSUE(4) ISSUE(5) ISSUE(6) ISSUE(7)
    asm volatile("s_waitcnt vmcnt(0)" ::: "memory");   // prologue drain: regs final
    __builtin_amdgcn_sched_barrier(0);

    for (int t = 0; t < TSTEPS; ++t) {
        const uint32_t TT = (uint32_t)t << 16;
        uint32_t stale = 0;
        f32x4 acch0 = {0.f,0.f,0.f,0.f}, acch1 = {0.f,0.f,0.f,0.f};
        f32x4 accz0 = {0.f,0.f,0.f,0.f}, accz1 = {0.f,0.f,0.f,0.f};

        // pinned prefetch of region t+1 (t=999: dummy re-read of region 999, discarded)
        uint32_t nwh[4], nwz[4];
        const int tn = (t < TSTEPS - 1) ? t + 1 : t;
        const char* pa = (const char*)pj + ((((size_t)tn << 5) + b0)*2048 + j)*2;
        PF(0) PF(1) PF(2) PF(3)

        PROC_I(0,8,26)   PROC_I(1,9,26)   PROC_I(2,10,26)  PROC_I(3,11,26)
        PROC_I(4,12,26)  PROC_I(5,13,26)  PROC_I(6,14,26)  PROC_I(7,15,26)
        PROC_I(8,16,14)  PROC_I(9,17,14)  PROC_I(10,18,14) PROC_I(11,19,14)
        PROC_I(12,20,14) PROC_I(13,21,14) PROC_I(14,22,14) PROC_I(15,23,14)
        PROC_I(16,24,14) PROC_I(17,25,14) PROC_I(18,26,14) PROC_I(19,27,14)
        PROC_I(20,28,14) PROC_I(21,29,14) PROC_I(22,30,14) PROC_I(23,31,14)
        PROC_N(24,14) PROC_N(25,12) PROC_N(26,10) PROC_N(27,8)
        PROC_N(28,6)  PROC_N(29,4)  PROC_N(30,2)  PROC_N(31,0)

        // serial retry into temp regs (rare path; keeps chunk-reg lifetimes short)
        if (stale) {
            const uint32_t* pc = hb32 + ((t & 1) << 15) + cb;
            do {
                for (int ks = 0; ks < 32; ++ks) {
                    if (!((stale >> ks) & 1)) continue;
                    const uint32_t* rp = pc + ks*512;
                    uint4 ta, tc;
                    asm volatile("global_load_dwordx4 %0, %2, off sc0 sc1\n\t"
                                 "global_load_dwordx4 %1, %2, off offset:16 sc0 sc1\n\t"
                                 "s_waitcnt vmcnt(0)"
                                 : "=v"(ta), "=v"(tc) : "v"(rp) : "memory");
                    __builtin_amdgcn_sched_barrier(0);
                    bool okc = __all(VAL8(ta, tc) == 0);
                    if (okc) {
                        uint32_t p0 = __builtin_amdgcn_perm(ta.y, ta.x, 0x05040100u);
                        uint32_t p1 = __builtin_amdgcn_perm(ta.w, ta.z, 0x05040100u);
                        uint32_t p2 = __builtin_amdgcn_perm(tc.y, tc.x, 0x05040100u);
                        uint32_t p3 = __builtin_amdgcn_perm(tc.w, tc.z, 0x05040100u);
                        uint4 av4 = make_uint4(p0, p1, p2, p3);
                        bf16x8 av = __builtin_bit_cast(bf16x8, av4);
                        bf16x8 bh = __builtin_bit_cast(bf16x8, ubs[ks*64 + l]);
                        bf16x8 bz = __builtin_bit_cast(bf16x8, ubs[(32 + ks)*64 + l]);
                        if ((ks & 1) == 0) {
                            acch0 = __builtin_amdgcn_mfma_f32_16x16x32_bf16(av, bh, acch0, 0, 0, 0);
                            accz0 = __builtin_amdgcn_mfma_f32_16x16x32_bf16(av, bz, accz0, 0, 0, 0);
                        } else {
                            acch1 = __builtin_amdgcn_mfma_f32_16x16x32_bf16(av, bh, acch1, 0, 0, 0);
                            accz1 = __builtin_amdgcn_mfma_f32_16x16x32_bf16(av, bz, accz1, 0, 0, 0);
                        }
                        stale &= ~(1u << ks);
                    } else {
                        __builtin_amdgcn_s_sleep(1);
                    }
                }
            } while (stale);
        }

        // epilogue: compute h_{t+1}
        f32x4 acch = acch0 + acch1, accz = accz0 + accz1;
        uint32_t wv[4];
        const uint32_t tagn = (uint32_t)(t + 1) << 16;
        #pragma unroll
        for (int q = 0; q < 4; ++q) {
            float a  = acch[q] + bf2f((u16)whu[q]);
            float zl = accz[q] + bf2f((u16)wzu[q]);
            float z  = 1.0f / (1.0f + __expf(-zl));
            float hc = fmaxf(a, 0.0f) * dm[q];
            float hn = z * h[q] + (1.0f - z) * hc;
            h[q] = hn;
            wv[q] = tagn | (uint32_t)f2bf(hn);
        }

        // publish tagged h_{t+1} (4 stores, one base)
        uint32_t* wp = hb32 + (((t + 1) & 1) << 15) + pb;
        asm volatile("global_store_dword %0, %1, off sc0 sc1\n\t"
                     "global_store_dword %0, %2, off offset:32 sc0 sc1\n\t"
                     "global_store_dword %0, %3, off offset:64 sc0 sc1\n\t"
                     "global_store_dword %0, %4, off offset:96 sc0 sc1"
                     :: "v"(wp), "v"(wv[0]), "v"(wv[1]), "v"(wv[2]), "v"(wv[3])
                     : "memory");

        // issue next step's first 8 chunks
        if (t < TSTEPS - 1) {
            icur = hb32 + (((t + 1) & 1) << 15) + cb;
            ISSUE(0) ISSUE(1) ISSUE(2) ISSUE(3) ISSUE(4) ISSUE(5) ISSUE(6) ISSUE(7)
        }

        // DEFERRED f32 out-write: region t-1 (t=0: harmless write into dead xb)
        {
            float* ob = (t ? (out + (((size_t)(t - 1)) << 15)) : sink)
                        + (size_t)b0*1024 + j;
            #pragma unroll
            for (int q = 0; q < 4; ++q)
                asm volatile("global_store_dword %0, %1, off"
                             :: "v"(ob + q*1024),
                                "v"(__builtin_bit_cast(uint32_t, pout[q])) : "memory");
            #pragma unroll
            for (int q = 0; q < 4; ++q) pout[q] = h[q];
        }

        // pinned hand-off: projections for t+1 (after chain's vmcnt(0) in volatile order)
        CPJ(0) CPJ(1) CPJ(2) CPJ(3)
    }

    // final deferred write: region 999
    {
        float* ob = out + ((size_t)(TSTEPS - 1) << 15) + (size_t)b0*1024 + j;
        #pragma unroll
        for (int q = 0; q < 4; ++q)
            asm volatile("global_store_dword %0, %1, off"
                         :: "v"(ob + q*1024),
                            "v"(__builtin_bit_cast(uint32_t, pout[q])) : "memory");
    }
}

extern "C" void kernel_launch(void* const* d_in, const int* in_sizes, int n_in,
                              void* d_out, int out_size, void* d_ws, size_t ws_size,
                              hipStream_t stream) {
    const float* x    = (const float*)d_in[0];
    const float* wh_w = (const float*)d_in[1];
    const float* wh_b = (const float*)d_in[2];
    const float* wz_w = (const float*)d_in[3];
    const float* wz_b = (const float*)d_in[4];
    const float* uh_w = (const float*)d_in[5];
    const float* uz_w = (const float*)d_in[6];
    const float* drop = (const float*)d_in[7];

    char* ws = (char*)d_ws;
    u16*      xb    = (u16*)ws;                               // 65,536,000 B
    u16*      wqT   = (u16*)(ws + 65536000);                  //  4,194,304 B
    u16*      upack = (u16*)(ws + 65536000 + 4194304);        //  4,194,304 B
    uint32_t* hb32  = (uint32_t*)(ws + 65536000 + 8388608);   //    262,144 B

    hipMemsetAsync(hb32, 0, 262144, stream);    // BOTH parities: tag 0, h_0 = 0

    k_convert_x  <<<16000, 256, 0, stream>>>(x, xb, 4096000);
    k_build_wq   <<<1024, 256, 0, stream>>>(wh_w, wz_w, wqT);
    k_build_upack<<<1024, 256, 0, stream>>>(uh_w, uz_w, upack);
    k_gemm       <<<4000, 256, 0, stream>>>(xb, wqT, wh_b, wz_b, (u16*)d_out);
    k_rec        <<<NBLK, 128, 0, stream>>>(upack, hb32, drop, (float*)d_out, (float*)xb);
}

// Round 9
// 6429.153 us; speedup vs baseline: 1.8448x; 1.8448x over previous
//
#include <hip/hip_runtime.h>
#include <stdint.h>

typedef unsigned short u16;
typedef __attribute__((ext_vector_type(8))) __bf16 bf16x8;
typedef __attribute__((ext_vector_type(4))) float f32x4;
typedef __attribute__((ext_vector_type(4))) uint32_t u32x4;

#define NBLK 64          // recurrence blocks (each owns 16 h-columns)
#define TSTEPS 1000

__device__ __forceinline__ u16 f2bf(float f) {
    uint32_t u = __builtin_bit_cast(uint32_t, f);
    u += 0x7fffu + ((u >> 16) & 1u);
    return (u16)(u >> 16);
}
__device__ __forceinline__ float bf2f(u16 s) {
    uint32_t u = ((uint32_t)s) << 16;
    return __builtin_bit_cast(float, u);
}

// quaternion block tables: W[ci*256+a][cj*256+b] = sgn[ci][cj] * w[comp[ci][cj]][a][b]
__device__ const int   q_comp[4][4] = {{0,1,2,3},{1,0,3,2},{2,3,0,1},{3,2,1,0}};
__device__ const float q_sgn [4][4] = {{ 1.f, 1.f, 1.f, 1.f},
                                       {-1.f, 1.f, 1.f,-1.f},
                                       {-1.f,-1.f, 1.f, 1.f},
                                       {-1.f, 1.f,-1.f, 1.f}};

// ---------------- x (f32) -> bf16 ----------------
__global__ void k_convert_x(const float* __restrict__ x, u16* __restrict__ xb, int n8) {
    int i = blockIdx.x * blockDim.x + threadIdx.x;
    if (i >= n8) return;
    const float4* p = (const float4*)x;
    float4 v0 = p[2*i], v1 = p[2*i + 1];
    u16 o[8];
    o[0]=f2bf(v0.x); o[1]=f2bf(v0.y); o[2]=f2bf(v0.z); o[3]=f2bf(v0.w);
    o[4]=f2bf(v1.x); o[5]=f2bf(v1.y); o[6]=f2bf(v1.z); o[7]=f2bf(v1.w);
    *(uint4*)(xb + (size_t)i*8) = *(uint4*)o;
}

// ---------------- build WqT [2048][1024] bf16 (row n = output col, k-contiguous) -----
__global__ void k_build_wq(const float* __restrict__ wh_w, const float* __restrict__ wz_w,
                           u16* __restrict__ wqT) {
    int tid = blockIdx.x * blockDim.x + threadIdx.x;   // 0..262143
    int n = tid >> 7, kg = tid & 127;
    const float* src = (n < 1024) ? wh_w : wz_w;
    int nn = n & 1023;
    int cj = nn >> 8, b = nn & 255;
    int k0 = kg << 3;
    int ci = k0 >> 8, a0 = k0 & 255;
    int c = q_comp[ci][cj];
    float s = q_sgn[ci][cj];
    const float* sp = src + c*65536 + a0*256 + b;
    u16 o[8];
    #pragma unroll
    for (int e = 0; e < 8; ++e) o[e] = f2bf(s * sp[e*256]);
    *(uint4*)(wqT + (size_t)n*1024 + k0) = *(uint4*)o;
}

// ---------------- build U pack: [blk][nt][ks][lane][8] bf16 (MFMA B-fragment order) --
__global__ void k_build_upack(const float* __restrict__ uh_w, const float* __restrict__ uz_w,
                              u16* __restrict__ upack) {
    int tid = blockIdx.x * blockDim.x + threadIdx.x;   // 0..262143
    int l   = tid & 63;
    int ks  = (tid >> 6) & 31;
    int nt  = (tid >> 11) & 1;
    int blk = tid >> 12;
    int j   = (blk << 4) + (l & 15);        // U column
    int k0  = (ks << 5) + ((l >> 4) << 3);  // U row base
    int ci = k0 >> 8, a0 = k0 & 255;
    int cj = j >> 8, b = j & 255;
    const float* src = nt ? uz_w : uh_w;
    int c = q_comp[ci][cj];
    float s = q_sgn[ci][cj];
    const float* sp = src + c*65536 + a0*256 + b;
    u16 o[8];
    #pragma unroll
    for (int e = 0; e < 8; ++e) o[e] = f2bf(s * sp[e*256]);
    *(uint4*)(upack + (size_t)tid*8) = *(uint4*)o;
}

// ---------------- phase-1 GEMM: C[32000][2048] bf16 = x_bf16 @ WqT^T + bias ----------
__global__ __launch_bounds__(256) void k_gemm(
        const u16* __restrict__ A, const u16* __restrict__ Bt,
        const float* __restrict__ whb, const float* __restrict__ wzb,
        u16* __restrict__ C)
{
    __shared__ __align__(16) u16 lsA[128*32];
    __shared__ __align__(16) u16 lsB[128*32];
    int bid = blockIdx.x;
    int swz = (bid & 7) * 500 + (bid >> 3);   // XCD swizzle (4000 = 8*500, bijective)
    int mi = swz >> 4, ni = swz & 15;
    int m0 = mi << 7, n0 = ni << 7;
    int tid = threadIdx.x;
    int w = tid >> 6, l = tid & 63;
    int wm = w >> 1, wn = w & 1;
    f32x4 acc[4][4];
    #pragma unroll
    for (int i = 0; i < 4; ++i)
        #pragma unroll
        for (int j = 0; j < 4; ++j) acc[i][j] = (f32x4){0.f,0.f,0.f,0.f};

    for (int kt = 0; kt < 32; ++kt) {
        int k0 = kt << 5;
        #pragma unroll
        for (int r = 0; r < 2; ++r) {
            int c = r*256 + w*64 + l;
            const u16* ga = A + (size_t)(m0 + (c >> 2))*1024 + k0 + (c & 3)*8;
            __builtin_amdgcn_global_load_lds(
                (const __attribute__((address_space(1))) uint32_t*)ga,
                (__attribute__((address_space(3))) uint32_t*)((char*)lsA + r*4096 + w*1024),
                16, 0, 0);
            const u16* gb = Bt + (size_t)(n0 + (c >> 2))*1024 + k0 + (c & 3)*8;
            __builtin_amdgcn_global_load_lds(
                (const __attribute__((address_space(1))) uint32_t*)gb,
                (__attribute__((address_space(3))) uint32_t*)((char*)lsB + r*4096 + w*1024),
                16, 0, 0);
        }
        __syncthreads();
        uint4 af[4], bfr[4];
        #pragma unroll
        for (int i = 0; i < 4; ++i) {
            int rowa = wm*64 + i*16 + (l & 15);
            af[i]  = *(const uint4*)((const char*)lsA + rowa*64 + (l >> 4)*16);
            int rowb = wn*64 + i*16 + (l & 15);
            bfr[i] = *(const uint4*)((const char*)lsB + rowb*64 + (l >> 4)*16);
        }
        #pragma unroll
        for (int i = 0; i < 4; ++i)
            #pragma unroll
            for (int j = 0; j < 4; ++j)
                acc[i][j] = __builtin_amdgcn_mfma_f32_16x16x32_bf16(
                    __builtin_bit_cast(bf16x8, af[i]),
                    __builtin_bit_cast(bf16x8, bfr[j]),
                    acc[i][j], 0, 0, 0);
        __syncthreads();
    }
    #pragma unroll
    for (int j = 0; j < 4; ++j) {
        int col = n0 + wn*64 + j*16 + (l & 15);
        float bias = (col < 1024) ? whb[col] : wzb[col - 1024];
        #pragma unroll
        for (int i = 0; i < 4; ++i) {
            int rowm = m0 + wm*64 + i*16 + ((l >> 4) << 2);
            #pragma unroll
            for (int q = 0; q < 4; ++q)
                C[(size_t)(rowm + q)*2048 + col] = f2bf(acc[i][j][q] + bias);
        }
    }
}

// ---------------- phase-2: the recurrence -------------------------------------------
// 64 blocks x 128 threads (2 waves). Block owns 16 h-columns; U slice in LDS.
// Flag barrier (per-wave u16 flags, 1 coalesced poll load) + bulk coalesced h
// exchange. Per step: poll -> issue 32 chunk loads + pinned PF -> vmcnt(0) ->
// MFMA -> epilogue -> LDS-transpose tile -> 1 coalesced dwordx4 publish/lane
// (32 lanes) -> vmcnt(0) -> flag store -> (off-path) deferred out f32 + handoff.

// pinned prefetch of next step's projections (2 loads per q: wh @0, wz @2048B)
#define PF(Q) \
    asm volatile("global_load_ushort %0, %2, off\n\t" \
                 "global_load_ushort %1, %2, off offset:2048" \
                 : "=v"(nwh[Q]), "=v"(nwz[Q]) : "v"(pa + (Q)*4096) : "memory");

__global__ __launch_bounds__(128, 1) void k_rec(
        const u16* __restrict__ upack,
        u16* __restrict__ hb,              // 2 * 32768 u16 (A-frag packed); parity 0 zeroed
        uint32_t* __restrict__ flags,      // 64 u32 = 128 u16 per-wave flags, zeroed
        const float* __restrict__ drop,    // [32][1024]
        float* __restrict__ out)           // d_out; also holds phase-1 bf16 [32000][2048]
{
    __shared__ __align__(16) uint4 ubs[4096];     // 64 KB U slice
    __shared__ __align__(16) u16 tx[512];         // 2 waves x 256: publish transpose
    const int tid = threadIdx.x;
    const int blk = blockIdx.x;
    const int mt = tid >> 6, l = tid & 63;
    const int wid = (blk << 1) + mt;              // wave id 0..127

    const uint4* ug = (const uint4*)upack + (size_t)blk*4096;
    #pragma unroll 4
    for (int r = 0; r < 32; ++r) ubs[r*128 + tid] = ug[r*128 + tid];

    const int j  = (blk << 4) + (l & 15);            // owned h column
    const int b0 = (mt << 4) + ((l >> 4) << 2);      // producer batch-row base
    float h[4]    = {0.f,0.f,0.f,0.f};
    float pout[4] = {0.f,0.f,0.f,0.f};               // deferred out values (h of step t-1)
    float dm[4];
    #pragma unroll
    for (int q = 0; q < 4; ++q) dm[q] = drop[(b0 + q)*1024 + j];

    const u16* pj = (const u16*)out;   // [32000][2048] bf16 (phase-1 result)
    uint32_t whu[4], wzu[4];
    #pragma unroll
    for (int q = 0; q < 4; ++q) {      // projections for t=0 (pre-publish: race-free)
        size_t rowp = (size_t)(b0 + q) * 2048;
        whu[q] = pj[rowp + j];
        wzu[q] = pj[rowp + 1024 + j];
    }
    // consumer byte base (chunk ks adds 1024 B); parity stride 65536 B
    const uint32_t cb  = (uint32_t)(mt*32768 + l*16);
    // producer byte base: chunk blk>>1 of region mt, half (blk&1), lane-slot (l&31)
    const uint32_t pbb = (uint32_t)((mt*32 + (blk >> 1))*1024 + (blk & 1)*512 + (l & 31)*16);

    __syncthreads();   // ubs ready (only sync in the kernel)

    for (int t = 0; t < TSTEPS; ++t) {
        // ---- barrier: wait until every wave has published h_t (flags >= t) ----
        {
            uint32_t fv;
            bool ok;
            do {
                fv = __hip_atomic_load(&flags[l], __ATOMIC_RELAXED, __HIP_MEMORY_SCOPE_AGENT);
                ok = ((fv & 0xFFFFu) >= (uint32_t)t) && ((fv >> 16) >= (uint32_t)t);
            } while (!__all(ok));
        }

        // ---- issue all 32 h-chunk loads (coherent) + pinned projection prefetch ----
        u32x4 hv[32];
        const char* cp = (const char*)hb + ((t & 1) << 16) + cb;
        #pragma unroll
        for (int ks = 0; ks < 32; ++ks)
            asm volatile("global_load_dwordx4 %0, %1, off sc0 sc1"
                         : "=v"(hv[ks]) : "v"(cp + ks*1024) : "memory");
        uint32_t nwh[4], nwz[4];
        if (t < TSTEPS - 1) {
            const char* pa = (const char*)pj + ((((size_t)(t + 1) << 5) + b0)*2048 + j)*2;
            PF(0) PF(1) PF(2) PF(3)
        }
        asm volatile("s_waitcnt vmcnt(0)" ::: "memory");
        __builtin_amdgcn_sched_barrier(0);

        // ---- MFMA chain (2 interleaved dependency chains) ----
        f32x4 acch0 = {0.f,0.f,0.f,0.f}, acch1 = {0.f,0.f,0.f,0.f};
        f32x4 accz0 = {0.f,0.f,0.f,0.f}, accz1 = {0.f,0.f,0.f,0.f};
        #pragma unroll
        for (int ks = 0; ks < 32; ++ks) {
            bf16x8 av = __builtin_bit_cast(bf16x8, hv[ks]);
            bf16x8 bh = __builtin_bit_cast(bf16x8, ubs[ks*64 + l]);
            bf16x8 bz = __builtin_bit_cast(bf16x8, ubs[(32 + ks)*64 + l]);
            if (ks & 1) {
                acch1 = __builtin_amdgcn_mfma_f32_16x16x32_bf16(av, bh, acch1, 0, 0, 0);
                accz1 = __builtin_amdgcn_mfma_f32_16x16x32_bf16(av, bz, accz1, 0, 0, 0);
            } else {
                acch0 = __builtin_amdgcn_mfma_f32_16x16x32_bf16(av, bh, acch0, 0, 0, 0);
                accz0 = __builtin_amdgcn_mfma_f32_16x16x32_bf16(av, bz, accz0, 0, 0, 0);
            }
        }

        // ---- epilogue: h_{t+1}; stage tile into LDS in consumer-packed order ----
        f32x4 acch = acch0 + acch1, accz = accz0 + accz1;
        u16* txw = tx + mt*256;
        #pragma unroll
        for (int q = 0; q < 4; ++q) {
            float a  = acch[q] + bf2f((u16)whu[q]);
            float zl = accz[q] + bf2f((u16)wzu[q]);
            float z  = 1.0f / (1.0f + __expf(-zl));
            float hc = fmaxf(a, 0.0f) * dm[q];
            float hn = z * h[q] + (1.0f - z) * hc;
            h[q] = hn;
            // dest slot: lane' = r + 16*(c>>3), elem = c&7 (r=(l>>4)*4+q, c=l&15)
            txw[(((l >> 4)*4 + q)*8) + ((l & 15) >> 3)*128 + (l & 7)] = f2bf(hn);
        }

        // ---- publish: one coalesced 16B store per lane (lanes 0..31) ----
        if (l < 32) {
            u32x4 pubv = *(const u32x4*)((const char*)tx + mt*512 + l*16);
            char* pp = (char*)hb + (((t + 1) & 1) << 16) + pbb;
            asm volatile("global_store_dwordx4 %0, %1, off sc0 sc1"
                         :: "v"(pp), "v"(pubv) : "memory");
        }
        asm volatile("s_waitcnt vmcnt(0)" ::: "memory");   // drain pub (+PF already done)
        if (l == 0) {
            u16* fp = (u16*)flags + wid;
            asm volatile("global_store_short %0, %1, off sc0 sc1"
                         :: "v"(fp), "v"((uint32_t)(t + 1)) : "memory");
        }

        // ---- off-critical-path: deferred f32 out (region t-1), handoff ----
        if (t > 0) {
            float* ob = out + (((size_t)(t - 1)) << 15) + (size_t)b0*1024 + j;
            #pragma unroll
            for (int q = 0; q < 4; ++q) ob[q*1024] = pout[q];
        }
        #pragma unroll
        for (int q = 0; q < 4; ++q) pout[q] = h[q];
        if (t < TSTEPS - 1) {
            #pragma unroll
            for (int q = 0; q < 4; ++q) { whu[q] = nwh[q]; wzu[q] = nwz[q]; }
        }
    }

    // final deferred write: region 999 (= h after input 999)
    {
        float* ob = out + (((size_t)(TSTEPS - 1)) << 15) + (size_t)b0*1024 + j;
        #pragma unroll
        for (int q = 0; q < 4; ++q) ob[q*1024] = pout[q];
    }
}

extern "C" void kernel_launch(void* const* d_in, const int* in_sizes, int n_in,
                              void* d_out, int out_size, void* d_ws, size_t ws_size,
                              hipStream_t stream) {
    const float* x    = (const float*)d_in[0];
    const float* wh_w = (const float*)d_in[1];
    const float* wh_b = (const float*)d_in[2];
    const float* wz_w = (const float*)d_in[3];
    const float* wz_b = (const float*)d_in[4];
    const float* uh_w = (const float*)d_in[5];
    const float* uz_w = (const float*)d_in[6];
    const float* drop = (const float*)d_in[7];

    char* ws = (char*)d_ws;
    u16*      xb    = (u16*)ws;                               // 65,536,000 B
    u16*      wqT   = (u16*)(ws + 65536000);                  //  4,194,304 B
    u16*      upack = (u16*)(ws + 65536000 + 4194304);        //  4,194,304 B
    u16*      hb    = (u16*)(ws + 65536000 + 8388608);        //    131,072 B
    uint32_t* flg   = (uint32_t*)(ws + 65536000 + 8388608 + 131072); // 256 B

    (void)hipMemsetAsync(flg, 0, 256, stream);        // all wave flags = 0
    (void)hipMemsetAsync(hb, 0, 65536, stream);       // parity 0: h_0 = 0

    k_convert_x  <<<16000, 256, 0, stream>>>(x, xb, 4096000);
    k_build_wq   <<<1024, 256, 0, stream>>>(wh_w, wz_w, wqT);
    k_build_upack<<<1024, 256, 0, stream>>>(uh_w, uz_w, upack);
    k_gemm       <<<4000, 256, 0, stream>>>(xb, wqT, wh_b, wz_b, (u16*)d_out);
    k_rec        <<<NBLK, 128, 0, stream>>>(upack, hb, flg, drop, (float*)d_out);
}

// Round 10
// 4874.410 us; speedup vs baseline: 2.4333x; 1.3190x over previous
//
#include <hip/hip_runtime.h>
#include <stdint.h>

typedef unsigned short u16;
typedef __attribute__((ext_vector_type(8))) __bf16 bf16x8;
typedef __attribute__((ext_vector_type(4))) float f32x4;
typedef __attribute__((ext_vector_type(4))) uint32_t u32x4;

#define NBLK 64          // recurrence blocks (each owns 16 h-columns)
#define TSTEPS 1000

__device__ __forceinline__ u16 f2bf(float f) {
    uint32_t u = __builtin_bit_cast(uint32_t, f);
    u += 0x7fffu + ((u >> 16) & 1u);
    return (u16)(u >> 16);
}
__device__ __forceinline__ float bf2f(u16 s) {
    uint32_t u = ((uint32_t)s) << 16;
    return __builtin_bit_cast(float, u);
}

// quaternion block tables: W[ci*256+a][cj*256+b] = sgn[ci][cj] * w[comp[ci][cj]][a][b]
__device__ const int   q_comp[4][4] = {{0,1,2,3},{1,0,3,2},{2,3,0,1},{3,2,1,0}};
__device__ const float q_sgn [4][4] = {{ 1.f, 1.f, 1.f, 1.f},
                                       {-1.f, 1.f, 1.f,-1.f},
                                       {-1.f,-1.f, 1.f, 1.f},
                                       {-1.f, 1.f,-1.f, 1.f}};

// ---------------- x (f32) -> bf16 ----------------
__global__ void k_convert_x(const float* __restrict__ x, u16* __restrict__ xb, int n8) {
    int i = blockIdx.x * blockDim.x + threadIdx.x;
    if (i >= n8) return;
    const float4* p = (const float4*)x;
    float4 v0 = p[2*i], v1 = p[2*i + 1];
    u16 o[8];
    o[0]=f2bf(v0.x); o[1]=f2bf(v0.y); o[2]=f2bf(v0.z); o[3]=f2bf(v0.w);
    o[4]=f2bf(v1.x); o[5]=f2bf(v1.y); o[6]=f2bf(v1.z); o[7]=f2bf(v1.w);
    *(uint4*)(xb + (size_t)i*8) = *(uint4*)o;
}

// ---------------- build WqT [2048][1024] bf16 (row n = output col, k-contiguous) -----
__global__ void k_build_wq(const float* __restrict__ wh_w, const float* __restrict__ wz_w,
                           u16* __restrict__ wqT) {
    int tid = blockIdx.x * blockDim.x + threadIdx.x;   // 0..262143
    int n = tid >> 7, kg = tid & 127;
    const float* src = (n < 1024) ? wh_w : wz_w;
    int nn = n & 1023;
    int cj = nn >> 8, b = nn & 255;
    int k0 = kg << 3;
    int ci = k0 >> 8, a0 = k0 & 255;
    int c = q_comp[ci][cj];
    float s = q_sgn[ci][cj];
    const float* sp = src + c*65536 + a0*256 + b;
    u16 o[8];
    #pragma unroll
    for (int e = 0; e < 8; ++e) o[e] = f2bf(s * sp[e*256]);
    *(uint4*)(wqT + (size_t)n*1024 + k0) = *(uint4*)o;
}

// ---------------- build U pack: [blk][nt][ks][lane][8] bf16 (MFMA B-fragment order) --
__global__ void k_build_upack(const float* __restrict__ uh_w, const float* __restrict__ uz_w,
                              u16* __restrict__ upack) {
    int tid = blockIdx.x * blockDim.x + threadIdx.x;   // 0..262143
    int l   = tid & 63;
    int ks  = (tid >> 6) & 31;
    int nt  = (tid >> 11) & 1;
    int blk = tid >> 12;
    int j   = (blk << 4) + (l & 15);        // U column
    int k0  = (ks << 5) + ((l >> 4) << 3);  // U row base
    int ci = k0 >> 8, a0 = k0 & 255;
    int cj = j >> 8, b = j & 255;
    const float* src = nt ? uz_w : uh_w;
    int c = q_comp[ci][cj];
    float s = q_sgn[ci][cj];
    const float* sp = src + c*65536 + a0*256 + b;
    u16 o[8];
    #pragma unroll
    for (int e = 0; e < 8; ++e) o[e] = f2bf(s * sp[e*256]);
    *(uint4*)(upack + (size_t)tid*8) = *(uint4*)o;
}

// ---------------- phase-1 GEMM: C[32000][2048] bf16 = x_bf16 @ WqT^T + bias ----------
__global__ __launch_bounds__(256) void k_gemm(
        const u16* __restrict__ A, const u16* __restrict__ Bt,
        const float* __restrict__ whb, const float* __restrict__ wzb,
        u16* __restrict__ C)
{
    __shared__ __align__(16) u16 lsA[128*32];
    __shared__ __align__(16) u16 lsB[128*32];
    int bid = blockIdx.x;
    int swz = (bid & 7) * 500 + (bid >> 3);   // XCD swizzle (4000 = 8*500, bijective)
    int mi = swz >> 4, ni = swz & 15;
    int m0 = mi << 7, n0 = ni << 7;
    int tid = threadIdx.x;
    int w = tid >> 6, l = tid & 63;
    int wm = w >> 1, wn = w & 1;
    f32x4 acc[4][4];
    #pragma unroll
    for (int i = 0; i < 4; ++i)
        #pragma unroll
        for (int j = 0; j < 4; ++j) acc[i][j] = (f32x4){0.f,0.f,0.f,0.f};

    for (int kt = 0; kt < 32; ++kt) {
        int k0 = kt << 5;
        #pragma unroll
        for (int r = 0; r < 2; ++r) {
            int c = r*256 + w*64 + l;
            const u16* ga = A + (size_t)(m0 + (c >> 2))*1024 + k0 + (c & 3)*8;
            __builtin_amdgcn_global_load_lds(
                (const __attribute__((address_space(1))) uint32_t*)ga,
                (__attribute__((address_space(3))) uint32_t*)((char*)lsA + r*4096 + w*1024),
                16, 0, 0);
            const u16* gb = Bt + (size_t)(n0 + (c >> 2))*1024 + k0 + (c & 3)*8;
            __builtin_amdgcn_global_load_lds(
                (const __attribute__((address_space(1))) uint32_t*)gb,
                (__attribute__((address_space(3))) uint32_t*)((char*)lsB + r*4096 + w*1024),
                16, 0, 0);
        }
        __syncthreads();
        uint4 af[4], bfr[4];
        #pragma unroll
        for (int i = 0; i < 4; ++i) {
            int rowa = wm*64 + i*16 + (l & 15);
            af[i]  = *(const uint4*)((const char*)lsA + rowa*64 + (l >> 4)*16);
            int rowb = wn*64 + i*16 + (l & 15);
            bfr[i] = *(const uint4*)((const char*)lsB + rowb*64 + (l >> 4)*16);
        }
        #pragma unroll
        for (int i = 0; i < 4; ++i)
            #pragma unroll
            for (int j = 0; j < 4; ++j)
                acc[i][j] = __builtin_amdgcn_mfma_f32_16x16x32_bf16(
                    __builtin_bit_cast(bf16x8, af[i]),
                    __builtin_bit_cast(bf16x8, bfr[j]),
                    acc[i][j], 0, 0, 0);
        __syncthreads();
    }
    #pragma unroll
    for (int j = 0; j < 4; ++j) {
        int col = n0 + wn*64 + j*16 + (l & 15);
        float bias = (col < 1024) ? whb[col] : wzb[col - 1024];
        #pragma unroll
        for (int i = 0; i < 4; ++i) {
            int rowm = m0 + wm*64 + i*16 + ((l >> 4) << 2);
            #pragma unroll
            for (int q = 0; q < 4; ++q)
                C[(size_t)(rowm + q)*2048 + col] = f2bf(acc[i][j][q] + bias);
        }
    }
}

// ---------------- phase-2: the recurrence -------------------------------------------
// 64 blocks x 128 threads (2 waves). Block owns 16 h-columns; U slice in LDS.
// The two batch-halves (wave mt=0/1) are INDEPENDENT exchange systems: wave mt
// consumes only chunks produced by same-mt waves, so it polls only the 64
// same-mt flags. Per step:
//   pre-poll: deferred out f32 stores (region t-1) + pinned PF (region t+1)
//             -> latency hides under the flag spin
//   poll 64 same-mt flags >= t (1 dword/lane)
//   issue 32 x dwordx4 sc0 sc1 h-loads -> vmcnt(0) -> 64 MFMA -> epilogue
//   LDS-transpose tile -> 1 coalesced 16B publish/lane (lanes<32) -> vmcnt(0)
//   (drains only the publish) -> flag store (t+1)

// pinned prefetch of next step's projections (2 loads per q: wh @0, wz @2048B)
#define PF(Q) \
    asm volatile("global_load_ushort %0, %2, off\n\t" \
                 "global_load_ushort %1, %2, off offset:2048" \
                 : "=v"(nwh[Q]), "=v"(nwz[Q]) : "v"(pa + (Q)*4096) : "memory");

__global__ __launch_bounds__(128, 1) void k_rec(
        const u16* __restrict__ upack,
        u16* __restrict__ hb,              // 2 * 32768 u16 (A-frag packed); parity 0 zeroed
        uint32_t* __restrict__ flags,      // 128 u32: [mt*64 + blk], zeroed
        const float* __restrict__ drop,    // [32][1024]
        float* __restrict__ out)           // d_out; also holds phase-1 bf16 [32000][2048]
{
    __shared__ __align__(16) uint4 ubs[4096];     // 64 KB U slice
    __shared__ __align__(16) u16 tx[512];         // 2 waves x 256: publish transpose
    const int tid = threadIdx.x;
    const int blk = blockIdx.x;
    const int mt = tid >> 6, l = tid & 63;

    const uint4* ug = (const uint4*)upack + (size_t)blk*4096;
    #pragma unroll 4
    for (int r = 0; r < 32; ++r) ubs[r*128 + tid] = ug[r*128 + tid];

    const int j  = (blk << 4) + (l & 15);            // owned h column
    const int b0 = (mt << 4) + ((l >> 4) << 2);      // producer batch-row base
    float h[4]    = {0.f,0.f,0.f,0.f};
    float pout[4] = {0.f,0.f,0.f,0.f};               // deferred out values (h of step t-1)
    float dm[4];
    #pragma unroll
    for (int q = 0; q < 4; ++q) dm[q] = drop[(b0 + q)*1024 + j];

    const u16* pj = (const u16*)out;   // [32000][2048] bf16 (phase-1 result)
    uint32_t whu[4], wzu[4];
    #pragma unroll
    for (int q = 0; q < 4; ++q) {      // projections for t=0 (pre-publish: race-free)
        size_t rowp = (size_t)(b0 + q) * 2048;
        whu[q] = pj[rowp + j];
        wzu[q] = pj[rowp + 1024 + j];
    }
    // consumer byte base (chunk ks adds 1024 B); parity stride 65536 B
    const uint32_t cb  = (uint32_t)(mt*32768 + l*16);
    // producer byte base: chunk blk>>1 of region mt, half (blk&1), lane-slot (l&31)
    const uint32_t pbb = (uint32_t)((mt*32 + (blk >> 1))*1024 + (blk & 1)*512 + (l & 31)*16);
    // per-mt flag slices
    const uint32_t* fpoll = flags + mt*64;
    uint32_t* fme = flags + mt*64 + blk;

    __syncthreads();   // ubs ready (only sync in the kernel)

    for (int t = 0; t < TSTEPS; ++t) {
        // ---- pre-poll issue phase (latency hidden under the flag spin) ----
        if (t > 0) {   // deferred f32 out: region t-1 (readers done >= 1 step ago)
            float* ob = out + (((size_t)(t - 1)) << 15) + (size_t)b0*1024 + j;
            #pragma unroll
            for (int q = 0; q < 4; ++q)
                asm volatile("global_store_dword %0, %1, off"
                             :: "v"(ob + q*1024),
                                "v"(__builtin_bit_cast(uint32_t, pout[q])) : "memory");
        }
        uint32_t nwh[4], nwz[4];
        if (t < TSTEPS - 1) {   // pinned PF of region t+1 projections
            const char* pa = (const char*)pj + ((((size_t)(t + 1) << 5) + b0)*2048 + j)*2;
            PF(0) PF(1) PF(2) PF(3)
        }

        // ---- barrier: wait until all 64 same-mt waves published h_t ----
        {
            uint32_t fv;
            do {
                fv = __hip_atomic_load(fpoll + l, __ATOMIC_RELAXED, __HIP_MEMORY_SCOPE_AGENT);
            } while (!__all(fv >= (uint32_t)t));
        }

        // ---- issue all 32 h-chunk loads (coherent) ----
        u32x4 hv[32];
        const char* cp = (const char*)hb + ((t & 1) << 16) + cb;
        #pragma unroll
        for (int ks = 0; ks < 32; ++ks)
            asm volatile("global_load_dwordx4 %0, %1, off sc0 sc1"
                         : "=v"(hv[ks]) : "v"(cp + ks*1024) : "memory");
        asm volatile("s_waitcnt vmcnt(0)" ::: "memory");
        __builtin_amdgcn_sched_barrier(0);

        // ---- MFMA chain (2 interleaved dependency chains) ----
        f32x4 acch0 = {0.f,0.f,0.f,0.f}, acch1 = {0.f,0.f,0.f,0.f};
        f32x4 accz0 = {0.f,0.f,0.f,0.f}, accz1 = {0.f,0.f,0.f,0.f};
        #pragma unroll
        for (int ks = 0; ks < 32; ++ks) {
            bf16x8 av = __builtin_bit_cast(bf16x8, hv[ks]);
            bf16x8 bh = __builtin_bit_cast(bf16x8, ubs[ks*64 + l]);
            bf16x8 bz = __builtin_bit_cast(bf16x8, ubs[(32 + ks)*64 + l]);
            if (ks & 1) {
                acch1 = __builtin_amdgcn_mfma_f32_16x16x32_bf16(av, bh, acch1, 0, 0, 0);
                accz1 = __builtin_amdgcn_mfma_f32_16x16x32_bf16(av, bz, accz1, 0, 0, 0);
            } else {
                acch0 = __builtin_amdgcn_mfma_f32_16x16x32_bf16(av, bh, acch0, 0, 0, 0);
                accz0 = __builtin_amdgcn_mfma_f32_16x16x32_bf16(av, bz, accz0, 0, 0, 0);
            }
        }

        // ---- epilogue: h_{t+1}; stage tile into LDS in consumer-packed order ----
        f32x4 acch = acch0 + acch1, accz = accz0 + accz1;
        u16* txw = tx + mt*256;
        #pragma unroll
        for (int q = 0; q < 4; ++q) {
            float a  = acch[q] + bf2f((u16)whu[q]);
            float zl = accz[q] + bf2f((u16)wzu[q]);
            float z  = 1.0f / (1.0f + __expf(-zl));
            float hc = fmaxf(a, 0.0f) * dm[q];
            float hn = z * h[q] + (1.0f - z) * hc;
            h[q] = hn;
            // dest slot: lane' = r + 16*(c>>3), elem = c&7 (r=(l>>4)*4+q, c=l&15)
            txw[(((l >> 4)*4 + q)*8) + ((l & 15) >> 3)*128 + (l & 7)] = f2bf(hn);
        }

        // ---- publish: one coalesced 16B store per lane (lanes 0..31) ----
        if (l < 32) {
            u32x4 pubv = *(const u32x4*)((const char*)tx + mt*512 + l*16);
            char* pp = (char*)hb + (((t + 1) & 1) << 16) + pbb;
            asm volatile("global_store_dwordx4 %0, %1, off sc0 sc1"
                         :: "v"(pp), "v"(pubv) : "memory");
        }
        asm volatile("s_waitcnt vmcnt(0)" ::: "memory");   // drains only the publish
        if (l == 0)
            asm volatile("global_store_dword %0, %1, off sc0 sc1"
                         :: "v"(fme), "v"((uint32_t)(t + 1)) : "memory");

        // ---- register hand-off ----
        #pragma unroll
        for (int q = 0; q < 4; ++q) pout[q] = h[q];
        if (t < TSTEPS - 1) {
            #pragma unroll
            for (int q = 0; q < 4; ++q) { whu[q] = nwh[q]; wzu[q] = nwz[q]; }
        }
    }

    // final deferred write: region 999 (= h after input 999)
    {
        float* ob = out + (((size_t)(TSTEPS - 1)) << 15) + (size_t)b0*1024 + j;
        #pragma unroll
        for (int q = 0; q < 4; ++q) ob[q*1024] = pout[q];
    }
}

extern "C" void kernel_launch(void* const* d_in, const int* in_sizes, int n_in,
                              void* d_out, int out_size, void* d_ws, size_t ws_size,
                              hipStream_t stream) {
    const float* x    = (const float*)d_in[0];
    const float* wh_w = (const float*)d_in[1];
    const float* wh_b = (const float*)d_in[2];
    const float* wz_w = (const float*)d_in[3];
    const float* wz_b = (const float*)d_in[4];
    const float* uh_w = (const float*)d_in[5];
    const float* uz_w = (const float*)d_in[6];
    const float* drop = (const float*)d_in[7];

    char* ws = (char*)d_ws;
    u16*      xb    = (u16*)ws;                               // 65,536,000 B
    u16*      wqT   = (u16*)(ws + 65536000);                  //  4,194,304 B
    u16*      upack = (u16*)(ws + 65536000 + 4194304);        //  4,194,304 B
    u16*      hb    = (u16*)(ws + 65536000 + 8388608);        //    131,072 B
    uint32_t* flg   = (uint32_t*)(ws + 65536000 + 8388608 + 131072); // 512 B

    (void)hipMemsetAsync(flg, 0, 512, stream);        // all flags = 0
    (void)hipMemsetAsync(hb, 0, 65536, stream);       // parity 0: h_0 = 0

    k_convert_x  <<<16000, 256, 0, stream>>>(x, xb, 4096000);
    k_build_wq   <<<1024, 256, 0, stream>>>(wh_w, wz_w, wqT);
    k_build_upack<<<1024, 256, 0, stream>>>(uh_w, uz_w, upack);
    k_gemm       <<<4000, 256, 0, stream>>>(xb, wqT, wh_b, wz_b, (u16*)d_out);
    k_rec        <<<NBLK, 128, 0, stream>>>(upack, hb, flg, drop, (float*)d_out);
}